// Round 2
// baseline (873.561 us; speedup 1.0000x reference)
//
#include <hip/hip_runtime.h>

#define NPTS 8192
#define DIM 256
#define KC 16384
#define NBLK 128   // number of code-blocks (KC / TN)
#define TM 128
#define TN 128
#define BK 16

// ---------------- transpose z [8,256,32,32] -> zf [8192,256] ----------------
__global__ __launch_bounds__(256) void k_transpose(const float* __restrict__ z,
                                                   float* __restrict__ zf) {
    __shared__ float t[32][33];
    const int hw0 = blockIdx.x * 32;
    const int d0  = blockIdx.y * 32;
    const int b   = blockIdx.z;
    const int tx = threadIdx.x & 31, ty = threadIdx.x >> 5;
#pragma unroll
    for (int i = 0; i < 4; i++) {
        const int d = d0 + ty + 8 * i;
        t[ty + 8 * i][tx] = z[(b * 256 + d) * 1024 + hw0 + tx];
    }
    __syncthreads();
#pragma unroll
    for (int i = 0; i < 4; i++) {
        const int hw = hw0 + ty + 8 * i;
        zf[(size_t)(b * 1024 + hw) * DIM + d0 + tx] = t[tx][ty + 8 * i];
    }
}

// ---------------- rownorm[r] = ||src[r]||^2 (256-dim rows) ----------------
__global__ __launch_bounds__(256) void k_rownorm(const float* __restrict__ src,
                                                 float* __restrict__ dst) {
    const int wave = threadIdx.x >> 6, lane = threadIdx.x & 63;
    const int row = blockIdx.x * 4 + wave;
    const float4 v = *(const float4*)(src + (size_t)row * DIM + lane * 4);
    float s = v.x * v.x + v.y * v.y + v.z * v.z + v.w * v.w;
#pragma unroll
    for (int m = 1; m < 64; m <<= 1) s += __shfl_xor(s, m, 64);
    if (lane == 0) dst[row] = s;
}

// ---------------- main: per (row, code-block) argmin of fp32((zn+en)-2*dot) ----------------
__global__ __launch_bounds__(256) void k_score(const float* __restrict__ zf,
                                               const float* __restrict__ emb,
                                               const float* __restrict__ enorm,
                                               const float* __restrict__ znorm,
                                               float* __restrict__ pval,
                                               int* __restrict__ pidx) {
    __shared__ float As[BK][TM];
    __shared__ float Bs[BK][TN];
    const int bx = blockIdx.x, by = blockIdx.y;
    const int t = threadIdx.x;
    const int tx = t & 15, ty = t >> 4;
    const int row0 = bx * TM, col0 = by * TN;

    float acc[8][8];
#pragma unroll
    for (int r = 0; r < 8; r++)
#pragma unroll
        for (int c = 0; c < 8; c++) acc[r][c] = 0.f;

    for (int kk = 0; kk < DIM; kk += BK) {
#pragma unroll
        for (int s = 0; s < 2; s++) {
            const int slot = t + s * 256;       // 0..511
            const int m = slot >> 2, kq = slot & 3;
            const float4 a = *(const float4*)(zf + (size_t)(row0 + m) * DIM + kk + kq * 4);
            As[kq * 4 + 0][m] = a.x; As[kq * 4 + 1][m] = a.y;
            As[kq * 4 + 2][m] = a.z; As[kq * 4 + 3][m] = a.w;
            const float4 bb = *(const float4*)(emb + (size_t)(col0 + m) * DIM + kk + kq * 4);
            Bs[kq * 4 + 0][m] = bb.x; Bs[kq * 4 + 1][m] = bb.y;
            Bs[kq * 4 + 2][m] = bb.z; Bs[kq * 4 + 3][m] = bb.w;
        }
        __syncthreads();
#pragma unroll
        for (int k = 0; k < BK; k++) {
            const float4 a0 = *(const float4*)&As[k][ty * 8];
            const float4 a1 = *(const float4*)&As[k][ty * 8 + 4];
            const float4 b0 = *(const float4*)&Bs[k][tx * 8];
            const float4 b1 = *(const float4*)&Bs[k][tx * 8 + 4];
            const float av[8] = {a0.x, a0.y, a0.z, a0.w, a1.x, a1.y, a1.z, a1.w};
            const float bv[8] = {b0.x, b0.y, b0.z, b0.w, b1.x, b1.y, b1.z, b1.w};
#pragma unroll
            for (int r = 0; r < 8; r++)
#pragma unroll
                for (int c = 0; c < 8; c++) acc[r][c] += av[r] * bv[c];
        }
        __syncthreads();
    }

    // epilogue: replicate numpy fp32 semantics:
    //   s = fp32( fp32(znorm + enorm) - fp32(2*dot) )
    // (2*dot is exact in fp32; possible fma contraction of t-2*acc is
    //  bit-identical to the two-step form for that reason)
    float en[8];
#pragma unroll
    for (int c = 0; c < 8; c++) en[c] = enorm[col0 + tx * 8 + c];

#pragma unroll
    for (int r = 0; r < 8; r++) {
        const int row = row0 + ty * 8 + r;
        const float zn = znorm[row];
        float bvl = 3.0e38f;
        int bil = 0x7fffffff;
#pragma unroll
        for (int c = 0; c < 8; c++) {
            const float tt = zn + en[c];
            const float s = tt - 2.0f * acc[r][c];
            if (s < bvl) { bvl = s; bil = col0 + tx * 8 + c; }  // strict <: smallest c wins ties
        }
        // reduce across tx (same wave, xor on low 4 lane bits)
#pragma unroll
        for (int m = 1; m <= 8; m <<= 1) {
            const float ov = __shfl_xor(bvl, m, 64);
            const int oi = __shfl_xor(bil, m, 64);
            if (ov < bvl || (ov == bvl && oi < bil)) { bvl = ov; bil = oi; }
        }
        if (tx == 0) {
            pval[(size_t)row * NBLK + by] = bvl;
            pidx[(size_t)row * NBLK + by] = bil;
        }
    }
}

// ---------------- reduce 128 partials per row -> final idx ----------------
__global__ __launch_bounds__(256) void k_reduce(const float* __restrict__ pval,
                                                const int* __restrict__ pidx,
                                                int* __restrict__ idxi,
                                                float* __restrict__ out_idx) {
    const int wv = threadIdx.x >> 6, lane = threadIdx.x & 63;
    const int row = blockIdx.x * 4 + wv;
    float bv = pval[(size_t)row * NBLK + lane];
    int bi = pidx[(size_t)row * NBLK + lane];
    const float v2 = pval[(size_t)row * NBLK + 64 + lane];
    const int i2 = pidx[(size_t)row * NBLK + 64 + lane];
    if (v2 < bv || (v2 == bv && i2 < bi)) { bv = v2; bi = i2; }
#pragma unroll
    for (int m = 1; m < 64; m <<= 1) {
        const float ov = __shfl_xor(bv, m, 64);
        const int oi = __shfl_xor(bi, m, 64);
        if (ov < bv || (ov == bv && oi < bi)) { bv = ov; bi = oi; }
    }
    if (lane == 0) {
        idxi[row] = bi;
        out_idx[row] = (float)bi;
    }
}

// ---------------- gather z_q (NCHW) + loss partials ----------------
__global__ __launch_bounds__(256) void k_gather(const float* __restrict__ emb,
                                                const float* __restrict__ zf,
                                                const int* __restrict__ idxi,
                                                float* __restrict__ zq,
                                                float* __restrict__ loss_part) {
    __shared__ float t[32][33];
    const int hw0 = blockIdx.x * 32;   // 32 tiles
    const int c0  = blockIdx.y * 32;   // 8 tiles
    const int b   = blockIdx.z;        // 8
    const int tx = threadIdx.x & 31, ty = threadIdx.x >> 5;
    float lsum = 0.f;
#pragma unroll
    for (int i = 0; i < 4; i++) {
        const int hh = ty + 8 * i;
        const int n = b * 1024 + hw0 + hh;
        const int id = idxi[n];
        const float q = emb[(size_t)id * DIM + c0 + tx];
        const float zv = zf[(size_t)n * DIM + c0 + tx];
        const float d = q - zv;
        lsum += d * d;
        t[hh][tx] = q;
    }
    __syncthreads();
#pragma unroll
    for (int i = 0; i < 4; i++) {
        const int c = c0 + ty + 8 * i;
        zq[(size_t)(b * 256 + c) * 1024 + hw0 + tx] = t[tx][ty + 8 * i];
    }
#pragma unroll
    for (int m = 1; m < 64; m <<= 1) lsum += __shfl_xor(lsum, m, 64);
    __shared__ float wsum[4];
    const int lane = threadIdx.x & 63, w = threadIdx.x >> 6;
    if (lane == 0) wsum[w] = lsum;
    __syncthreads();
    if (threadIdx.x == 0) {
        const int bid = (blockIdx.z * gridDim.y + blockIdx.y) * gridDim.x + blockIdx.x;
        loss_part[bid] = wsum[0] + wsum[1] + wsum[2] + wsum[3];
    }
}

// ---------------- finalize loss ----------------
__global__ __launch_bounds__(256) void k_final(const float* __restrict__ loss_part,
                                               float* __restrict__ out_loss) {
    float s = 0.f;
    for (int i = threadIdx.x; i < 2048; i += 256) s += loss_part[i];
#pragma unroll
    for (int m = 1; m < 64; m <<= 1) s += __shfl_xor(s, m, 64);
    __shared__ float wsum[4];
    const int lane = threadIdx.x & 63, w = threadIdx.x >> 6;
    if (lane == 0) wsum[w] = s;
    __syncthreads();
    if (threadIdx.x == 0) {
        out_loss[0] = 1.25f * (wsum[0] + wsum[1] + wsum[2] + wsum[3]) / 2097152.0f;
    }
}

extern "C" void kernel_launch(void* const* d_in, const int* in_sizes, int n_in,
                              void* d_out, int out_size, void* d_ws, size_t ws_size,
                              hipStream_t stream) {
    const float* z   = (const float*)d_in[0];   // [8,256,32,32]
    const float* emb = (const float*)d_in[1];   // [16384,256]
    float* out = (float*)d_out;
    float* ws  = (float*)d_ws;

    // ws layout (floats):
    float* zf    = ws;                       // 2,097,152
    float* enorm = ws + 2097152;             // 16,384
    float* znorm = ws + 2113536;             // 8,192
    float* pval  = ws + 2121728;             // 1,048,576
    int*   pidx  = (int*)(ws + 3170304);     // 1,048,576
    int*   idxi  = (int*)(ws + 4218880);     // 8,192
    float* lossp = ws + 4227072;             // 2,048
    // total ~16.9 MB

    float* zq       = out;                   // [8,256,32,32] NCHW
    float* out_loss = out + 2097152;         // scalar
    float* out_idx  = out + 2097153;         // [8192] as float32

    k_transpose<<<dim3(32, 8, 8), 256, 0, stream>>>(z, zf);
    k_rownorm<<<dim3(4096), 256, 0, stream>>>(emb, enorm);
    k_rownorm<<<dim3(2048), 256, 0, stream>>>(zf, znorm);
    k_score<<<dim3(64, 128), 256, 0, stream>>>(zf, emb, enorm, znorm, pval, pidx);
    k_reduce<<<dim3(2048), 256, 0, stream>>>(pval, pidx, idxi, out_idx);
    k_gather<<<dim3(32, 8, 8), 256, 0, stream>>>(emb, zf, idxi, zq, lossp);
    k_final<<<1, 256, 0, stream>>>(lossp, out_loss);
}

// Round 3
// 485.009 us; speedup vs baseline: 1.8011x; 1.8011x over previous
//
#include <hip/hip_runtime.h>

#define DIM 256

typedef __bf16 bf8v __attribute__((ext_vector_type(8)));
typedef float f4v __attribute__((ext_vector_type(4)));

__device__ inline unsigned short f2bf(float x) {
    unsigned u = __float_as_uint(x);
    u += 0x7fffu + ((u >> 16) & 1u);   // RNE
    return (unsigned short)(u >> 16);
}

// ---------------- transpose z [8,256,32,32] -> zf [8192,256] ----------------
__global__ __launch_bounds__(256) void k_transpose(const float* __restrict__ z,
                                                   float* __restrict__ zf) {
    __shared__ float t[32][33];
    const int hw0 = blockIdx.x * 32;
    const int d0  = blockIdx.y * 32;
    const int b   = blockIdx.z;
    const int tx = threadIdx.x & 31, ty = threadIdx.x >> 5;
#pragma unroll
    for (int i = 0; i < 4; i++) {
        const int d = d0 + ty + 8 * i;
        t[ty + 8 * i][tx] = z[(b * 256 + d) * 1024 + hw0 + tx];
    }
    __syncthreads();
#pragma unroll
    for (int i = 0; i < 4; i++) {
        const int hw = hw0 + ty + 8 * i;
        zf[(size_t)(b * 1024 + hw) * DIM + d0 + tx] = t[tx][ty + 8 * i];
    }
}

// ---------------- rownorm[r] = ||src[r]||^2 ----------------
__global__ __launch_bounds__(256) void k_rownorm(const float* __restrict__ src,
                                                 float* __restrict__ dst) {
    const int wave = threadIdx.x >> 6, lane = threadIdx.x & 63;
    const int row = blockIdx.x * 4 + wave;
    const float4 v = *(const float4*)(src + (size_t)row * DIM + lane * 4);
    float s = v.x * v.x + v.y * v.y + v.z * v.z + v.w * v.w;
#pragma unroll
    for (int m = 1; m < 64; m <<= 1) s += __shfl_xor(s, m, 64);
    if (lane == 0) dst[row] = s;
}

// ---------------- fp32 -> bf16 conversion (4 elems/thread) ----------------
__global__ __launch_bounds__(256) void k_cvt(const float* __restrict__ src,
                                             unsigned short* __restrict__ dst) {
    const size_t i = ((size_t)blockIdx.x * 256 + threadIdx.x) * 4;
    const float4 v = *(const float4*)(src + i);
    ushort4 o;
    o.x = f2bf(v.x); o.y = f2bf(v.y); o.z = f2bf(v.z); o.w = f2bf(v.w);
    *(ushort4*)(dst + i) = o;
}

// ---------------- bf16 MFMA scoring: pval[row][g] = min approx score over 64-code group g --------
__global__ __launch_bounds__(256) void k_mfma_score(
        const unsigned short* __restrict__ zb, const unsigned short* __restrict__ eb,
        const float* __restrict__ znorm, const float* __restrict__ enorm,
        float* __restrict__ pval) {
    __shared__ unsigned short As[128 * 32];
    __shared__ unsigned short Bs[128 * 32];
    const int row0 = blockIdx.x * 128;
    const int col0 = blockIdx.y * 128;
    const int t = threadIdx.x;
    const int lane = t & 63;
    const int wave = t >> 6;
    const int wr = wave >> 1, wc = wave & 1;     // wave computes rows [wr*64,+64) x cols [wc*64,+64)
    const int q = lane >> 4, m15 = lane & 15;

    f4v acc[4][4];
#pragma unroll
    for (int rt = 0; rt < 4; rt++)
#pragma unroll
        for (int ct = 0; ct < 4; ct++) acc[rt][ct] = (f4v){0.f, 0.f, 0.f, 0.f};

    // staging: slot s (0..511) loads 16B: global row (s>>2), k-offset (s&3)*8
    const unsigned short* gA0 = zb + (size_t)(row0 + (t >> 2)) * DIM + (t & 3) * 8;
    const unsigned short* gA1 = zb + (size_t)(row0 + 64 + (t >> 2)) * DIM + (t & 3) * 8;
    const unsigned short* gB0 = eb + (size_t)(col0 + (t >> 2)) * DIM + (t & 3) * 8;
    const unsigned short* gB1 = eb + (size_t)(col0 + 64 + (t >> 2)) * DIM + (t & 3) * 8;
    unsigned short* lA0 = &As[t * 8];
    unsigned short* lA1 = &As[t * 8 + 2048];
    unsigned short* lB0 = &Bs[t * 8];
    unsigned short* lB1 = &Bs[t * 8 + 2048];

    for (int kk = 0; kk < DIM; kk += 32) {
        __builtin_amdgcn_global_load_lds((const __attribute__((address_space(1))) void*)(gA0 + kk),
                                         (__attribute__((address_space(3))) void*)lA0, 16, 0, 0);
        __builtin_amdgcn_global_load_lds((const __attribute__((address_space(1))) void*)(gA1 + kk),
                                         (__attribute__((address_space(3))) void*)lA1, 16, 0, 0);
        __builtin_amdgcn_global_load_lds((const __attribute__((address_space(1))) void*)(gB0 + kk),
                                         (__attribute__((address_space(3))) void*)lB0, 16, 0, 0);
        __builtin_amdgcn_global_load_lds((const __attribute__((address_space(1))) void*)(gB1 + kk),
                                         (__attribute__((address_space(3))) void*)lB1, 16, 0, 0);
        __syncthreads();
        bf8v af[4], bfv[4];
#pragma unroll
        for (int rt = 0; rt < 4; rt++)
            af[rt] = *(bf8v*)&As[(wr * 64 + rt * 16 + m15) * 32 + q * 8];
#pragma unroll
        for (int ct = 0; ct < 4; ct++)
            bfv[ct] = *(bf8v*)&Bs[(wc * 64 + ct * 16 + m15) * 32 + q * 8];
#pragma unroll
        for (int rt = 0; rt < 4; rt++)
#pragma unroll
            for (int ct = 0; ct < 4; ct++)
                acc[rt][ct] = __builtin_amdgcn_mfma_f32_16x16x32_bf16(af[rt], bfv[ct], acc[rt][ct], 0, 0, 0);
        __syncthreads();
    }

    // epilogue: approx score s = (zn + en) - 2*dot; min over this wave's 64 cols per row
    float en_l[4];
#pragma unroll
    for (int ct = 0; ct < 4; ct++) en_l[ct] = enorm[col0 + wc * 64 + ct * 16 + m15];
    const int gcol = blockIdx.y * 2 + wc;
#pragma unroll
    for (int rt = 0; rt < 4; rt++) {
#pragma unroll
        for (int j = 0; j < 4; j++) {
            const int row = row0 + wr * 64 + rt * 16 + q * 4 + j;
            const float zn = znorm[row];
            float s = (zn + en_l[0]) - 2.0f * acc[rt][0][j];
#pragma unroll
            for (int ct = 1; ct < 4; ct++)
                s = fminf(s, (zn + en_l[ct]) - 2.0f * acc[rt][ct][j]);
#pragma unroll
            for (int m = 1; m <= 8; m <<= 1) s = fminf(s, __shfl_xor(s, m, 64));
            if (m15 == 0) pval[(size_t)row * 256 + gcol] = s;
        }
    }
}

// ---------------- rescue: exact fp32 re-score of flagged 64-code groups ----------------
__global__ __launch_bounds__(256) void k_rescue(
        const float* __restrict__ zf, const float* __restrict__ emb,
        const float* __restrict__ znorm, const float* __restrict__ enorm,
        const float* __restrict__ pval, int* __restrict__ idxi,
        float* __restrict__ out_idx) {
    const int row = blockIdx.x;
    const int t = threadIdx.x;
    const int lane = t & 63, w = t >> 6;
    __shared__ float zs[256];
    __shared__ float wmin[4];
    __shared__ int nflag;
    __shared__ short list[256];
    __shared__ float rv[4];
    __shared__ int ri[4];

    zs[t] = zf[(size_t)row * DIM + t];
    if (t == 0) nflag = 0;
    const float gv = pval[(size_t)row * 256 + t];
    float mv = gv;
#pragma unroll
    for (int m = 1; m < 64; m <<= 1) mv = fminf(mv, __shfl_xor(mv, m, 64));
    if (lane == 0) wmin[w] = mv;
    __syncthreads();
    const float g = fminf(fminf(wmin[0], wmin[1]), fminf(wmin[2], wmin[3])) + 1.5e-4f;
    if (gv <= g) { int p = atomicAdd(&nflag, 1); list[p] = (short)t; }
    __syncthreads();

    const float zn = znorm[row];
    float bv = 3.0e38f;
    int bi = 0x7fffffff;
    const int n = nflag;
    for (int i = 0; i < n; i++) {
        const int gi = list[i];
        const int code = gi * 64 + (t >> 2);
        const float* ep = emb + (size_t)code * DIM + (t & 3) * 64;
        const float* zp = zs + (t & 3) * 64;
        float d = 0.f;
#pragma unroll
        for (int k = 0; k < 64; k += 4) {
            const float4 e = *(const float4*)(ep + k);
            d = fmaf(zp[k], e.x, d);
            d = fmaf(zp[k + 1], e.y, d);
            d = fmaf(zp[k + 2], e.z, d);
            d = fmaf(zp[k + 3], e.w, d);
        }
        d += __shfl_xor(d, 1, 64);
        d += __shfl_xor(d, 2, 64);
        const float tt = zn + enorm[code];
        const float s = tt - 2.0f * d;   // exact fp32 semantics (2*d exact)
        if (s < bv || (s == bv && code < bi)) { bv = s; bi = code; }
    }
#pragma unroll
    for (int m = 1; m < 64; m <<= 1) {
        const float ov = __shfl_xor(bv, m, 64);
        const int oi = __shfl_xor(bi, m, 64);
        if (ov < bv || (ov == bv && oi < bi)) { bv = ov; bi = oi; }
    }
    if (lane == 0) { rv[w] = bv; ri[w] = bi; }
    __syncthreads();
    if (t == 0) {
        for (int w2 = 1; w2 < 4; w2++)
            if (rv[w2] < bv || (rv[w2] == bv && ri[w2] < bi)) { bv = rv[w2]; bi = ri[w2]; }
        idxi[row] = bi;
        out_idx[row] = (float)bi;
    }
}

// ---------------- gather z_q (NCHW) + loss partials ----------------
__global__ __launch_bounds__(256) void k_gather(const float* __restrict__ emb,
                                                const float* __restrict__ zf,
                                                const int* __restrict__ idxi,
                                                float* __restrict__ zq,
                                                float* __restrict__ loss_part) {
    __shared__ float t[32][33];
    const int hw0 = blockIdx.x * 32;
    const int c0  = blockIdx.y * 32;
    const int b   = blockIdx.z;
    const int tx = threadIdx.x & 31, ty = threadIdx.x >> 5;
    float lsum = 0.f;
#pragma unroll
    for (int i = 0; i < 4; i++) {
        const int hh = ty + 8 * i;
        const int n = b * 1024 + hw0 + hh;
        const int id = idxi[n];
        const float q = emb[(size_t)id * DIM + c0 + tx];
        const float zv = zf[(size_t)n * DIM + c0 + tx];
        const float d = q - zv;
        lsum += d * d;
        t[hh][tx] = q;
    }
    __syncthreads();
#pragma unroll
    for (int i = 0; i < 4; i++) {
        const int c = c0 + ty + 8 * i;
        zq[(size_t)(b * 256 + c) * 1024 + hw0 + tx] = t[tx][ty + 8 * i];
    }
#pragma unroll
    for (int m = 1; m < 64; m <<= 1) lsum += __shfl_xor(lsum, m, 64);
    __shared__ float wsum[4];
    const int lane = threadIdx.x & 63, w = threadIdx.x >> 6;
    if (lane == 0) wsum[w] = lsum;
    __syncthreads();
    if (threadIdx.x == 0) {
        const int bid = (blockIdx.z * gridDim.y + blockIdx.y) * gridDim.x + blockIdx.x;
        loss_part[bid] = wsum[0] + wsum[1] + wsum[2] + wsum[3];
    }
}

// ---------------- finalize loss ----------------
__global__ __launch_bounds__(256) void k_final(const float* __restrict__ loss_part,
                                               float* __restrict__ out_loss) {
    float s = 0.f;
    for (int i = threadIdx.x; i < 2048; i += 256) s += loss_part[i];
#pragma unroll
    for (int m = 1; m < 64; m <<= 1) s += __shfl_xor(s, m, 64);
    __shared__ float wsum[4];
    const int lane = threadIdx.x & 63, w = threadIdx.x >> 6;
    if (lane == 0) wsum[w] = s;
    __syncthreads();
    if (threadIdx.x == 0) {
        out_loss[0] = 1.25f * (wsum[0] + wsum[1] + wsum[2] + wsum[3]) / 2097152.0f;
    }
}

extern "C" void kernel_launch(void* const* d_in, const int* in_sizes, int n_in,
                              void* d_out, int out_size, void* d_ws, size_t ws_size,
                              hipStream_t stream) {
    const float* z   = (const float*)d_in[0];   // [8,256,32,32]
    const float* emb = (const float*)d_in[1];   // [16384,256]
    float* out = (float*)d_out;
    float* ws  = (float*)d_ws;

    // ws layout (float offsets):
    float*          zf    = ws;                                  // 2,097,152 (8 MB)
    float*          pval  = ws + 2097152;                        // 2,097,152 (8 MB)
    unsigned short* zb    = (unsigned short*)(ws + 4194304);     // 2M bf16 (4 MB)
    unsigned short* eb    = (unsigned short*)(ws + 5242880);     // 4M bf16 (8 MB)
    float*          enorm = ws + 7340032;                        // 16,384
    float*          znorm = ws + 7356416;                        // 8,192
    int*            idxi  = (int*)(ws + 7364608);                // 8,192
    float*          lossp = ws + 7372800;                        // 2,048
    // total ~29.5 MB

    float* zq       = out;                   // [8,256,32,32] NCHW
    float* out_loss = out + 2097152;         // scalar
    float* out_idx  = out + 2097153;         // [8192] as float32

    k_transpose<<<dim3(32, 8, 8), 256, 0, stream>>>(z, zf);
    k_rownorm<<<dim3(4096), 256, 0, stream>>>(emb, enorm);
    k_rownorm<<<dim3(2048), 256, 0, stream>>>(zf, znorm);
    k_cvt<<<dim3(2048), 256, 0, stream>>>(zf, zb);
    k_cvt<<<dim3(4096), 256, 0, stream>>>(emb, eb);
    k_mfma_score<<<dim3(64, 128), 256, 0, stream>>>(zb, eb, znorm, enorm, pval);
    k_rescue<<<dim3(8192), 256, 0, stream>>>(zf, emb, znorm, enorm, pval, idxi, out_idx);
    k_gather<<<dim3(32, 8, 8), 256, 0, stream>>>(emb, zf, idxi, zq, lossp);
    k_final<<<1, 256, 0, stream>>>(lossp, out_loss);
}

// Round 4
// 410.322 us; speedup vs baseline: 2.1290x; 1.1820x over previous
//
#include <hip/hip_runtime.h>
#include <hip/hip_fp16.h>

#define DIM 256
#define MARGIN 1.5e-4f
#define WLCAP 262144

typedef __bf16 bf8v __attribute__((ext_vector_type(8)));
typedef float f4v __attribute__((ext_vector_type(4)));

__device__ inline unsigned short f2bf(float x) {
    unsigned u = __float_as_uint(x);
    u += 0x7fffu + ((u >> 16) & 1u);   // RNE
    return (unsigned short)(u >> 16);
}

// ---------------- transpose z [8,256,32,32] -> zf [8192,256] fp32 + zb bf16 ----------------
__global__ __launch_bounds__(256) void k_zprep(const float* __restrict__ z,
                                               float* __restrict__ zf,
                                               unsigned short* __restrict__ zb) {
    __shared__ float t[32][33];
    const int hw0 = blockIdx.x * 32;
    const int d0  = blockIdx.y * 32;
    const int b   = blockIdx.z;
    const int tx = threadIdx.x & 31, ty = threadIdx.x >> 5;
#pragma unroll
    for (int i = 0; i < 4; i++) {
        const int d = d0 + ty + 8 * i;
        t[ty + 8 * i][tx] = z[(b * 256 + d) * 1024 + hw0 + tx];
    }
    __syncthreads();
#pragma unroll
    for (int i = 0; i < 4; i++) {
        const int hw = hw0 + ty + 8 * i;
        const float v = t[tx][ty + 8 * i];
        const size_t o = (size_t)(b * 1024 + hw) * DIM + d0 + tx;
        zf[o] = v;
        zb[o] = f2bf(v);
    }
}

// ---------------- emb -> eb bf16 + enorm; also zero worklist counter ----------------
__global__ __launch_bounds__(256) void k_eprep(const float* __restrict__ emb,
                                               unsigned short* __restrict__ eb,
                                               float* __restrict__ enorm,
                                               int* __restrict__ gcnt) {
    if (blockIdx.x == 0 && threadIdx.x == 0) gcnt[0] = 0;
    const int wave = threadIdx.x >> 6, lane = threadIdx.x & 63;
    const int row = blockIdx.x * 4 + wave;
    const float4 v = *(const float4*)(emb + (size_t)row * DIM + lane * 4);
    ushort4 o;
    o.x = f2bf(v.x); o.y = f2bf(v.y); o.z = f2bf(v.z); o.w = f2bf(v.w);
    *(ushort4*)(eb + (size_t)row * DIM + lane * 4) = o;
    float s = v.x * v.x + v.y * v.y + v.z * v.z + v.w * v.w;
#pragma unroll
    for (int m = 1; m < 64; m <<= 1) s += __shfl_xor(s, m, 64);
    if (lane == 0) enorm[row] = s;
}

// ---------------- rownorm over zf ----------------
__global__ __launch_bounds__(256) void k_rownorm(const float* __restrict__ src,
                                                 float* __restrict__ dst) {
    const int wave = threadIdx.x >> 6, lane = threadIdx.x & 63;
    const int row = blockIdx.x * 4 + wave;
    const float4 v = *(const float4*)(src + (size_t)row * DIM + lane * 4);
    float s = v.x * v.x + v.y * v.y + v.z * v.z + v.w * v.w;
#pragma unroll
    for (int m = 1; m < 64; m <<= 1) s += __shfl_xor(s, m, 64);
    if (lane == 0) dst[row] = s;
}

// ---------------- bf16 MFMA scoring: pvalh[row][g] = fp16(min srel over 16-code group g) --------
__global__ __launch_bounds__(256) void k_mfma_score(
        const unsigned short* __restrict__ zb, const unsigned short* __restrict__ eb,
        const float* __restrict__ znorm, const float* __restrict__ enorm,
        unsigned short* __restrict__ pvalh) {
    __shared__ unsigned short As[128 * 32];
    __shared__ unsigned short Bs[128 * 32];
    const int row0 = blockIdx.x * 128;
    const int col0 = blockIdx.y * 128;
    const int t = threadIdx.x;
    const int lane = t & 63;
    const int wave = t >> 6;
    const int wr = wave >> 1, wc = wave & 1;
    const int q = lane >> 4, m15 = lane & 15;

    f4v acc[4][4];
#pragma unroll
    for (int rt = 0; rt < 4; rt++)
#pragma unroll
        for (int ct = 0; ct < 4; ct++) acc[rt][ct] = (f4v){0.f, 0.f, 0.f, 0.f};

    const unsigned short* gA0 = zb + (size_t)(row0 + (t >> 2)) * DIM + (t & 3) * 8;
    const unsigned short* gA1 = zb + (size_t)(row0 + 64 + (t >> 2)) * DIM + (t & 3) * 8;
    const unsigned short* gB0 = eb + (size_t)(col0 + (t >> 2)) * DIM + (t & 3) * 8;
    const unsigned short* gB1 = eb + (size_t)(col0 + 64 + (t >> 2)) * DIM + (t & 3) * 8;
    unsigned short* lA0 = &As[t * 8];
    unsigned short* lA1 = &As[t * 8 + 2048];
    unsigned short* lB0 = &Bs[t * 8];
    unsigned short* lB1 = &Bs[t * 8 + 2048];

    for (int kk = 0; kk < DIM; kk += 32) {
        __builtin_amdgcn_global_load_lds((const __attribute__((address_space(1))) void*)(gA0 + kk),
                                         (__attribute__((address_space(3))) void*)lA0, 16, 0, 0);
        __builtin_amdgcn_global_load_lds((const __attribute__((address_space(1))) void*)(gA1 + kk),
                                         (__attribute__((address_space(3))) void*)lA1, 16, 0, 0);
        __builtin_amdgcn_global_load_lds((const __attribute__((address_space(1))) void*)(gB0 + kk),
                                         (__attribute__((address_space(3))) void*)lB0, 16, 0, 0);
        __builtin_amdgcn_global_load_lds((const __attribute__((address_space(1))) void*)(gB1 + kk),
                                         (__attribute__((address_space(3))) void*)lB1, 16, 0, 0);
        __syncthreads();
        bf8v af[4], bfv[4];
#pragma unroll
        for (int rt = 0; rt < 4; rt++)
            af[rt] = *(bf8v*)&As[(wr * 64 + rt * 16 + m15) * 32 + q * 8];
#pragma unroll
        for (int ct = 0; ct < 4; ct++)
            bfv[ct] = *(bf8v*)&Bs[(wc * 64 + ct * 16 + m15) * 32 + q * 8];
#pragma unroll
        for (int rt = 0; rt < 4; rt++)
#pragma unroll
            for (int ct = 0; ct < 4; ct++)
                acc[rt][ct] = __builtin_amdgcn_mfma_f32_16x16x32_bf16(af[rt], bfv[ct], acc[rt][ct], 0, 0, 0);
        __syncthreads();
    }

    // epilogue: srel = ((zn+en) - 2*dot) - zn, min over the 16 cols of each tile ct
    float en_l[4];
#pragma unroll
    for (int ct = 0; ct < 4; ct++) en_l[ct] = enorm[col0 + wc * 64 + ct * 16 + m15];
    unsigned short* sm = As;   // reuse as [128][8] halves
#pragma unroll
    for (int rt = 0; rt < 4; rt++) {
#pragma unroll
        for (int j = 0; j < 4; j++) {
            const int rl = wr * 64 + rt * 16 + q * 4 + j;
            const float zn = znorm[row0 + rl];
#pragma unroll
            for (int ct = 0; ct < 4; ct++) {
                float srel = ((zn + en_l[ct]) - 2.0f * acc[rt][ct][j]) - zn;
#pragma unroll
                for (int m = 1; m <= 8; m <<= 1) srel = fminf(srel, __shfl_xor(srel, m, 64));
                if (m15 == 0) sm[rl * 8 + wc * 4 + ct] = __half_as_ushort(__float2half_rn(srel));
            }
        }
    }
    __syncthreads();
    if (t < 128) {
        const uint4 v = *(const uint4*)&sm[t * 8];
        *(uint4*)&pvalh[(size_t)(row0 + t) * 1024 + blockIdx.y * 8] = v;
    }
}

// ---------------- flag: per row, min over 1024 group-mins; append flagged to worklist ------------
__global__ __launch_bounds__(256) void k_flag(const unsigned short* __restrict__ pvalh,
                                              unsigned long long* __restrict__ best64,
                                              int* __restrict__ wl, int* __restrict__ gcnt) {
    const int row = blockIdx.x;
    const int t = threadIdx.x;
    const int lane = t & 63, w = t >> 6;
    __shared__ float wmin[4];
    __shared__ int lcnt, lbase;
    __shared__ int llist[1024];
    if (t == 0) { lcnt = 0; best64[row] = 0xFFFFFFFFFFFFFFFFULL; }
    const __half* p = (const __half*)(pvalh + (size_t)row * 1024 + t * 4);
    float v[4];
#pragma unroll
    for (int k = 0; k < 4; k++) v[k] = __half2float(p[k]);
    float mn = fminf(fminf(v[0], v[1]), fminf(v[2], v[3]));
#pragma unroll
    for (int m = 1; m < 64; m <<= 1) mn = fminf(mn, __shfl_xor(mn, m, 64));
    if (lane == 0) wmin[w] = mn;
    __syncthreads();
    const float g = fminf(fminf(wmin[0], wmin[1]), fminf(wmin[2], wmin[3])) + MARGIN;
#pragma unroll
    for (int k = 0; k < 4; k++) {
        if (v[k] <= g) {
            const int pos = atomicAdd(&lcnt, 1);
            llist[pos] = (row << 10) | (t * 4 + k);
        }
    }
    __syncthreads();
    if (t == 0) lbase = atomicAdd(gcnt, lcnt);
    __syncthreads();
    for (int i = t; i < lcnt; i += 256) {
        const int d = lbase + i;
        if (d < WLCAP) wl[d] = llist[i];
    }
}

// ---------------- rescore: exact fp32 re-score of flagged 16-code groups ----------------
__global__ __launch_bounds__(256) void k_rescore(
        const float* __restrict__ zf, const float* __restrict__ emb,
        const float* __restrict__ znorm, const float* __restrict__ enorm,
        const int* __restrict__ wl, const int* __restrict__ gcnt,
        unsigned long long* __restrict__ best64) {
    const int count = min(gcnt[0], WLCAP);
    const int t = threadIdx.x;
    const int lane16 = t & 15, codei = t >> 4;
    for (int item = blockIdx.x; item < count; item += gridDim.x) {
        const int e = wl[item];
        const int row = e >> 10, g = e & 1023;
        const int code = g * 16 + codei;
        const float* zp = zf + (size_t)row * DIM + lane16 * 16;
        const float* ep = emb + (size_t)code * DIM + lane16 * 16;
        float d = 0.f;
#pragma unroll
        for (int k = 0; k < 16; k += 4) {
            const float4 ev = *(const float4*)(ep + k);
            const float4 zv = *(const float4*)(zp + k);
            d = fmaf(zv.x, ev.x, d);
            d = fmaf(zv.y, ev.y, d);
            d = fmaf(zv.z, ev.z, d);
            d = fmaf(zv.w, ev.w, d);
        }
#pragma unroll
        for (int m = 1; m <= 8; m <<= 1) d += __shfl_xor(d, m, 64);
        if (lane16 == 0) {
            const float tt = znorm[row] + enorm[code];
            const float s = tt - 2.0f * d;   // exact fp32 semantics
            const unsigned long long key =
                ((unsigned long long)__float_as_uint(s) << 32) | (unsigned)code;
            atomicMin(&best64[row], key);
        }
    }
}

// ---------------- out_idx from best64 ----------------
__global__ __launch_bounds__(256) void k_finalidx(const unsigned long long* __restrict__ best64,
                                                  float* __restrict__ out_idx) {
    const int i = blockIdx.x * 256 + threadIdx.x;
    out_idx[i] = (float)(unsigned)(best64[i] & 0xFFFFFFFFULL);
}

// ---------------- gather z_q (NCHW) + loss partials ----------------
__global__ __launch_bounds__(256) void k_gather(const float* __restrict__ emb,
                                                const float* __restrict__ zf,
                                                const unsigned long long* __restrict__ best64,
                                                float* __restrict__ zq,
                                                float* __restrict__ loss_part) {
    __shared__ float t[32][33];
    const int hw0 = blockIdx.x * 32;
    const int c0  = blockIdx.y * 32;
    const int b   = blockIdx.z;
    const int tx = threadIdx.x & 31, ty = threadIdx.x >> 5;
    float lsum = 0.f;
#pragma unroll
    for (int i = 0; i < 4; i++) {
        const int hh = ty + 8 * i;
        const int n = b * 1024 + hw0 + hh;
        const int id = (int)(best64[n] & 0xFFFFFFFFULL);
        const float q = emb[(size_t)id * DIM + c0 + tx];
        const float zv = zf[(size_t)n * DIM + c0 + tx];
        const float d = q - zv;
        lsum += d * d;
        t[hh][tx] = q;
    }
    __syncthreads();
#pragma unroll
    for (int i = 0; i < 4; i++) {
        const int c = c0 + ty + 8 * i;
        zq[(size_t)(b * 256 + c) * 1024 + hw0 + tx] = t[tx][ty + 8 * i];
    }
#pragma unroll
    for (int m = 1; m < 64; m <<= 1) lsum += __shfl_xor(lsum, m, 64);
    __shared__ float wsum[4];
    const int lane = threadIdx.x & 63, w = threadIdx.x >> 6;
    if (lane == 0) wsum[w] = lsum;
    __syncthreads();
    if (threadIdx.x == 0) {
        const int bid = (blockIdx.z * gridDim.y + blockIdx.y) * gridDim.x + blockIdx.x;
        loss_part[bid] = wsum[0] + wsum[1] + wsum[2] + wsum[3];
    }
}

// ---------------- finalize loss ----------------
__global__ __launch_bounds__(256) void k_final(const float* __restrict__ loss_part,
                                               float* __restrict__ out_loss) {
    float s = 0.f;
    for (int i = threadIdx.x; i < 2048; i += 256) s += loss_part[i];
#pragma unroll
    for (int m = 1; m < 64; m <<= 1) s += __shfl_xor(s, m, 64);
    __shared__ float wsum[4];
    const int lane = threadIdx.x & 63, w = threadIdx.x >> 6;
    if (lane == 0) wsum[w] = s;
    __syncthreads();
    if (threadIdx.x == 0) {
        out_loss[0] = 1.25f * (wsum[0] + wsum[1] + wsum[2] + wsum[3]) / 2097152.0f;
    }
}

extern "C" void kernel_launch(void* const* d_in, const int* in_sizes, int n_in,
                              void* d_out, int out_size, void* d_ws, size_t ws_size,
                              hipStream_t stream) {
    const float* z   = (const float*)d_in[0];   // [8,256,32,32]
    const float* emb = (const float*)d_in[1];   // [16384,256]
    float* out = (float*)d_out;
    float* ws  = (float*)d_ws;

    // ws layout (float-slot offsets):
    float*              zf    = ws;                                   // 2,097,152  (8 MB)
    unsigned short*     pvalh = (unsigned short*)(ws + 2097152);      // 8M halves  (16 MB)
    unsigned short*     zb    = (unsigned short*)(ws + 6291456);      // 2M halves  (4 MB)
    unsigned short*     eb    = (unsigned short*)(ws + 7340032);      // 4M halves  (8 MB)
    float*              enorm = ws + 9437184;                         // 16,384
    float*              znorm = ws + 9453568;                         // 8,192
    unsigned long long* best64= (unsigned long long*)(ws + 9461760);  // 8192 × 8 B
    int*                wl    = (int*)(ws + 9478144);                 // 262,144
    int*                gcnt  = (int*)(ws + 9740288);                 // 8
    float*              lossp = ws + 9740296;                         // 2,048
    // total ≈ 39 MB

    float* zq       = out;                   // [8,256,32,32] NCHW
    float* out_loss = out + 2097152;         // scalar
    float* out_idx  = out + 2097153;         // [8192] as float32

    k_zprep<<<dim3(32, 8, 8), 256, 0, stream>>>(z, zf, zb);
    k_eprep<<<dim3(4096), 256, 0, stream>>>(emb, eb, enorm, gcnt);
    k_rownorm<<<dim3(2048), 256, 0, stream>>>(zf, znorm);
    k_mfma_score<<<dim3(64, 128), 256, 0, stream>>>(zb, eb, znorm, enorm, pvalh);
    k_flag<<<dim3(8192), 256, 0, stream>>>(pvalh, best64, wl, gcnt);
    k_rescore<<<dim3(2048), 256, 0, stream>>>(zf, emb, znorm, enorm, wl, gcnt, best64);
    k_finalidx<<<dim3(32), 256, 0, stream>>>(best64, out_idx);
    k_gather<<<dim3(32, 8, 8), 256, 0, stream>>>(emb, zf, best64, zq, lossp);
    k_final<<<1, 256, 0, stream>>>(lossp, out_loss);
}